// Round 8
// baseline (214.650 us; speedup 1.0000x reference)
//
#include <hip/hip_runtime.h>

// Problem constants
#define BB 4
#define CC 32
#define LL 50176              // 224*224
#define KK2 25
#define CDTOT (BB * LL * KK2) // 5,017,600 floats in cd

// out[b,c2,l2] = in[b,c2,l2] * sum_k2 Wt(b,l2,k2) * V(b,n).
// Lanes stride l2 by 800 (l2 = rem + 800*ii, rem wave-uniform).
// KEY IDENTITY: ys*224 + xs = u  =>  unclamped gather addr
//     addr = A0(k2) + ii + 1568*c2,  A0 = c*LL + 224*dy + dx + e0  (WAVE-UNIFORM)
// x-OOB lanes read +-2 off (in-bounds within batch slab) but weight=0.
// => load is uniform_base[ii]: saddr form, 1 VALU + 1 load per MAC, A-table in SGPRs.
// Interior c2 in [1,30] always y-in-bounds; c2=0/31 via clamped special pass,
// HOISTED before the main loop (R8: shrinks live range -> lower VGPR).
// Stores PLAIN (R5: nontemporal stores defeated write-combining 25->97MB).
// R8: __launch_bounds__(256,5) -> <=102 VGPR -> 5 blocks/CU (20 waves, was 16).

__global__ __launch_bounds__(256, 5) void conv_local_kernel(
    const float* __restrict__ input,
    const float* __restrict__ cd,
    const float* __restrict__ colw,
    const float* __restrict__ posw,
    float* __restrict__ out)
{
    __shared__ float smem[64 * 101 + 8];  // 6472 floats: cd staging, then 2x2560 exchange

    const int t    = threadIdx.x;
    const int lane = t & 63;
    const int w    = t >> 6;              // wave 0..3 -> rem = rem0 + w

    // XCD-locality swizzle (validated R3: FETCH 211->42MB)
    const int bx   = blockIdx.x;          // 0..1599
    const int xcd  = bx & 7;
    const int slot = bx >> 3;             // 0..199
    const int b    = xcd >> 1;            // batch pinned to XCD pair
    const int j    = slot * 2 + (xcd & 1);// 0..399 within batch
    const int chunk  = j & 1;             // c2-chunk: [0,16) or [16,32)
    const int rem0   = (j >> 1) * 4;      // 0..796
    const int c2base = chunk * 16;

    const float cw = colw[0];
    const float pw = posw[0];
    const float* __restrict__ in_b  = input + b * (CC * LL);
    float* __restrict__       out_b = out   + b * (CC * LL);

    // ---- stage cd for this block's 256 l2 values, coalesced + nontemporal ----
    {
        const int cd_base = b * (LL * KK2);
        #pragma unroll
        for (int jld = 0; jld < 25; ++jld) {
            int flat = t + 256 * jld;            // [0, 6400)
            int ci   = flat / 100;               // ii 0..63
            int pos  = flat - ci * 100;          // (rem-rem0)*25 + k2
            int gidx = cd_base + (rem0 + 800 * ci) * KK2 + pos;
            gidx = min(gidx, CDTOT - 1);         // clamp OOB tail (values unused)
            smem[ci * 101 + pos] = __builtin_nontemporal_load(&cd[gidx]);
        }
    }
    __syncthreads();

    // ---- per-thread setup ----
    const int remU = __builtin_amdgcn_readfirstlane(rem0 + w);  // wave-uniform
    const int ii   = lane;

    float Wt[KK2];   // per-lane weight, x-mask folded in (fp32)
    int   A0u[KK2];  // WAVE-UNIFORM base: c*LL + 224*dy + dx + e0  (-> SGPRs)
    const float POS[KK2] = {8,5,4,5,8, 5,2,1,2,5, 4,1,0,1,4, 5,2,1,2,5, 8,5,4,5,8};

    #pragma unroll
    for (int k2 = 0; k2 < KK2; ++k2) {
        int t1 = 576 * k2 + remU;       // all scalar:
        int q0 = t1 / 800;
        int r  = t1 - q0 * 800;
        int c  = r / 25;
        int s  = r - c * 25;
        int dy = s / 5 - 2;
        int dx = s % 5 - 2;
        int e0 = 62 * k2 + q0;          // <= 1506
        A0u[k2] = c * LL + 224 * dy + dx + e0;
        int u  = e0 + ii;               // vector: +lane
        int ys = u / 224;               // [0,7]
        int xs = u - ys * 224;
        int xm = xs + dx;
        bool xok = (unsigned)xm < 224u;
        float wgt = fmaf(smem[ii * 101 + w * 25 + k2], cw, POS[k2] * pw);
        Wt[k2] = xok ? wgt : 0.0f;      // x-mask folded into weight
    }
    __syncthreads();   // smem reused as exchange buffer from here

    // ---- special channel (c2=0 for chunk0, c2=31 for chunk1): clamped +
    // y-masked pass, HOISTED so its temps don't overlap the gather loop ----
    float spAcc;
    {
        const bool sp0 = (chunk == 0);
        float a = 0.0f;
        #pragma unroll
        for (int k2 = 0; k2 < KK2; ++k2) {
            int t1 = 576 * k2 + remU;
            int q0 = t1 / 800;
            int r  = t1 - q0 * 800;
            int c  = r / 25;
            int s  = r - c * 25;
            int dy = s / 5 - 2;
            int dx = s % 5 - 2;
            int u  = 62 * k2 + q0 + ii;
            int ys = u / 224;
            int xs = u - ys * 224;
            int xc = min(max(xs + dx, 0), 223);
            int yy = ys + dy;                     // [-2, 9]
            int yb = sp0 ? max(yy, 0) : (217 + min(yy, 6));
            bool ok = sp0 ? (yy >= 0) : (yy <= 6);
            float v = in_b[c * LL + yb * 224 + xc];
            a = fmaf(ok ? v : 0.0f, Wt[k2], a);
        }
        spAcc = a;
    }

    // mapping B (contiguous-l2) constants for coalesced epilogue load/store
    const int remB = t & 3;
    const int iiB  = t >> 2;
    const int l2B  = rem0 + remB + 800 * iiB;
    const bool okB = l2B < LL;
    const int idxB = min(l2B, LL - 1);

    // ---- main loop: 2 groups of 8 channels ----
    #pragma unroll 1
    for (int gg = 0; gg < 2; ++gg) {
        float acc[8];
        #pragma unroll
        for (int g = 0; g < 8; ++g) acc[g] = 0.0f;

        // interior gathers: uniform base + lane offset -> saddr loads
        #pragma unroll
        for (int k2 = 0; k2 < KK2; ++k2) {
            const float wv = Wt[k2];
            #pragma unroll
            for (int g = 0; g < 8; ++g) {
                int c2  = c2base + gg * 8 + g;
                int c2e = min(max(c2, 1), 30);   // special slots: dummy interior read
                const float* bp = in_b + (A0u[k2] + 1568 * c2e);  // wave-uniform ptr
                acc[g] = fmaf(bp[ii], wv, acc[g]);
            }
        }

        // special channel result overwrites its slot
        const bool sp_here = (chunk == 0) ? (gg == 0) : (gg == 1);
        if (sp_here) {
            if (chunk == 0) acc[0] = spAcc; else acc[7] = spAcc;
        }

        // exchange to mapping B; strides 320/80 -> max 2-way LDS access (free)
        float* sbuf = smem + gg * 2560;
        #pragma unroll
        for (int g = 0; g < 8; ++g)
            sbuf[g * 320 + w * 80 + lane] = acc[g];
        __syncthreads();
        #pragma unroll
        for (int g = 0; g < 8; ++g) {
            const int oidx = (c2base + gg * 8 + g) * LL + idxB;
            float S = sbuf[g * 320 + remB * 80 + iiB];
            if (okB) out_b[oidx] = S * in_b[oidx];   // plain store (WRITE ideal)
        }
        // no trailing barrier: gg=1 uses a disjoint sbuf region
    }
}

extern "C" void kernel_launch(void* const* d_in, const int* in_sizes, int n_in,
                              void* d_out, int out_size, void* d_ws, size_t ws_size,
                              hipStream_t stream) {
    const float* input = (const float*)d_in[0];
    const float* cdist = (const float*)d_in[1];
    const float* cwp   = (const float*)d_in[2];
    const float* pwp   = (const float*)d_in[3];
    float* o = (float*)d_out;

    dim3 grid(1600);   // 4 b x 2 chunks x 200 rem0-tiles, XCD-pinned in-kernel
    dim3 block(256);
    hipLaunchKernelGGL(conv_local_kernel, grid, block, 0, stream,
                       input, cdist, cwp, pwp, o);
}